// Round 3
// baseline (1038.239 us; speedup 1.0000x reference)
//
#include <hip/hip_runtime.h>
#include <stdint.h>

// ---------------------------------------------------------------------------
// STGTCN layer: xt = relu(conv1(x)+b1 + sigmoid(conv2(x)+b2) + conv3(x)+b3)
//               x1 = A^T xt (over V), x2 = A^T x1
//               out = PReLU(W_out · concat(xt,x1,x2) + b_out)
// N=32, C=32, V=500 (pad 512), T=96 -> T'=94 (pad 96), C_OUT=64, GC=96
//
// Workspace layout (bf16 h-planes stored as [b=n*32+c][vblk=v/8][l(96)][v%8]
// so that MFMA B-fragments (k = v, 8-contiguous per lane) are 16B groups):
//   xt : S bytes       x1 : S       x2 : S       (S = 1024*64*96*8*2)
//   At : 512*512 bf16 (A^T, zero-padded => no masking in GEMMs)
//   Wa : conv weights bf16 repacked [koff][conv*32+co][ci]  (MFMA A-operand)
//   Wo : w_out bf16 [o][c]
// ---------------------------------------------------------------------------

typedef float  f32x4  __attribute__((ext_vector_type(4)));
typedef float  f32x2  __attribute__((ext_vector_type(2)));
typedef short  bf16x8 __attribute__((ext_vector_type(8)));

static __device__ __forceinline__ unsigned short f2bf(float f) {
    union { float f; unsigned u; } v; v.f = f;
    unsigned u = v.u;
    return (unsigned short)((u + 0x7fffu + ((u >> 16) & 1u)) >> 16);  // RTNE
}

#define WS_S   ((size_t)1024 * 64 * 96 * 8 * 2)   // one bf16 h-plane set
#define AT_B   (512u * 512u * 2u)
#define WA_B   (3u * 96u * 32u * 2u)              // 18KB bf16 conv weights

// swizzle of 16B k-slots within a 64B LDS row (kills frag-read bank conflicts)
static __device__ __forceinline__ int swz(int row, int q) {
    return q ^ (row & 3) ^ ((row >> 2) & 3);
}

// ---------------------------------------------------------------------------
// prep: build At (bf16, transposed, zero-padded), Wa (bf16 repack), Wo (bf16)
// ---------------------------------------------------------------------------
__global__ __launch_bounds__(256)
void prep_kernel(const float* __restrict__ A,
                 const float* __restrict__ w1, const float* __restrict__ w2,
                 const float* __restrict__ w3, const float* __restrict__ wout,
                 unsigned short* __restrict__ At, unsigned short* __restrict__ Wa,
                 unsigned short* __restrict__ Wo)
{
    int idx = blockIdx.x * 256 + threadIdx.x;
    if (idx < 512 * 512) {
        int w = idx >> 9, v = idx & 511;
        float val = (w < 500 && v < 500) ? A[v * 500 + w] : 0.f;  // At[w][v] = A[v][w]
        At[idx] = f2bf(val);
    } else if (idx < 512 * 512 + 3 * 3 * 32 * 32) {
        // Wa[t], t = ((koff*3 + conv)*32 + co)*32 + ci  ->  w_conv[co][ci][0][koff]
        int t = idx - 512 * 512;
        int ci = t & 31;
        int co = (t >> 5) & 31;
        int rc = t >> 10;            // koff*3 + conv
        int conv = rc % 3, koff = rc / 3;
        const float* ws = (conv == 0) ? w1 : ((conv == 1) ? w2 : w3);
        Wa[t] = f2bf(ws[co * 96 + ci * 3 + koff]);
    } else if (idx < 512 * 512 + 3 * 3 * 32 * 32 + 64 * 96) {
        int t = idx - (512 * 512 + 3 * 3 * 32 * 32);
        Wo[t] = f2bf(wout[t]);
    }
}

// ---------------------------------------------------------------------------
// conv (MFMA version): per block = (t-half th, vblk, n).
// GEMM: out[row = conv*32+co][col = ll*8+vv] = sum_ci Wa[koff][row][ci] *
//       X[ci][th*48+ll+koff][vv], accumulated over koff=0..2.
// M=96 (3convs x 32c), N=384 (48 l x 8 vv), K=32 per tap (one 16x16x32 MFMA).
// 8 waves, each owns 48 cols (3 n-tiles), all 6 m-tiles; A-frags in registers.
// Epilogue combines the 3 conv rows per lane (same lane/reg alignment),
// applies sigmoid gate + relu, stages to LDS, stores coalesced 16B runs.
// ---------------------------------------------------------------------------
__global__ __launch_bounds__(512, 1)
void conv_kernel(const float* __restrict__ x, const unsigned short* __restrict__ Wa,
                 const float* __restrict__ b1, const float* __restrict__ b2,
                 const float* __restrict__ b3, unsigned short* __restrict__ xt)
{
    __shared__ unsigned short Xs2[52 * 256];    // [tl][vv][ci] bf16, 26.6KB
    __shared__ unsigned short WaSh[9216];       // [koff][conv*32+co][ci], 18KB
    __shared__ unsigned short stash[32 * 408];  // [co][ll*8+vv] (stride 408 = pad), 26.1KB

    const int th   = blockIdx.x;    // 0..1 (t-half: cols l = th*48 .. th*48+47)
    const int vblk = blockIdx.y;    // 0..62
    const int n    = blockIdx.z;    // 0..31
    const int tid  = threadIdx.x;
    const int lane = tid & 63, wv = tid >> 6;
    const int cl = lane & 15, q4 = lane >> 4;
    const int nbase = wv * 48;

    // ---- stage Wa (18KB, coalesced 16B) ----
    for (int g = tid; g < 1152; g += 512)
        *(uint4*)&WaSh[g * 8] = *(const uint4*)(Wa + g * 8);

    // ---- stage + transpose x tile -> Xs2[tl][vv][ci] ----
    // thread quantum: (i-quad i4, vv) x 4 t's; 64 rows x 13 segs = 832 iters.
    for (int s = 0; s < 2; ++s) {
        int fid = tid + s * 512;
        if (fid < 832) {
            int rq = fid / 13, seg = fid % 13;
            int vv = rq & 7, i4 = rq >> 3;
            int v = vblk * 8 + vv;
            int tbase = th * 48 + seg * 4;
            float b[4][4];
            #pragma unroll
            for (int di = 0; di < 4; ++di) {
                float4 f = make_float4(0.f, 0.f, 0.f, 0.f);
                if (v < 500 && tbase < 96)
                    f = *(const float4*)(x + (((size_t)n * 32 + i4 * 4 + di) * 500 + v) * 96 + tbase);
                b[di][0] = f.x; b[di][1] = f.y; b[di][2] = f.z; b[di][3] = f.w;
            }
            #pragma unroll
            for (int j = 0; j < 4; ++j) {
                uint2 u;
                u.x = (unsigned)f2bf(b[0][j]) | ((unsigned)f2bf(b[1][j]) << 16);
                u.y = (unsigned)f2bf(b[2][j]) | ((unsigned)f2bf(b[3][j]) << 16);
                *(uint2*)&Xs2[(seg * 4 + j) * 256 + vv * 32 + i4 * 4] = u;
            }
        }
    }

    // bias preload (per-lane c's; L1/L2-hot)
    float bb1[2][4], bb2[2][4], bb3[2][4];
    #pragma unroll
    for (int p = 0; p < 2; ++p)
        #pragma unroll
        for (int r = 0; r < 4; ++r) {
            int c = p * 16 + q4 * 4 + r;
            bb1[p][r] = b1[c]; bb2[p][r] = b2[c]; bb3[p][r] = b3[c];
        }

    __syncthreads();

    // ---- A-fragments resident in registers: 6 m-tiles x 3 taps ----
    bf16x8 af[6][3];
    #pragma unroll
    for (int mt = 0; mt < 6; ++mt)
        #pragma unroll
        for (int ko = 0; ko < 3; ++ko)
            af[mt][ko] = *(const bf16x8*)&WaSh[ko * 3072 + (mt * 16 + cl) * 32 + q4 * 8];

    f32x4 acc[6][3];
    #pragma unroll
    for (int mt = 0; mt < 6; ++mt)
        #pragma unroll
        for (int nt = 0; nt < 3; ++nt)
            acc[mt][nt] = (f32x4){0.f, 0.f, 0.f, 0.f};

    // ---- main: 9 B-frag reads, 54 MFMAs, no K-loop ----
    #pragma unroll
    for (int ko = 0; ko < 3; ++ko) {
        #pragma unroll
        for (int nt = 0; nt < 3; ++nt) {
            int col = nbase + nt * 16 + cl;
            int ll = col >> 3, vv = col & 7;
            bf16x8 bf = *(const bf16x8*)&Xs2[(ll + ko) * 256 + vv * 32 + q4 * 8];
            #pragma unroll
            for (int mt = 0; mt < 6; ++mt)
                acc[mt][nt] = __builtin_amdgcn_mfma_f32_16x16x32_bf16(
                    af[mt][ko], bf, acc[mt][nt], 0, 0, 0);
        }
    }

    // ---- epilogue: rows (c, 32+c, 64+c) live in same lane, same reg r ----
    #pragma unroll
    for (int p = 0; p < 2; ++p) {
        #pragma unroll
        for (int nt = 0; nt < 3; ++nt) {
            int col = nbase + nt * 16 + cl;
            int ll = col >> 3, vv = col & 7;
            bool valid = (th * 48 + ll) < 94;
            #pragma unroll
            for (int r = 0; r < 4; ++r) {
                float a0 = acc[p][nt][r];         // conv1: rows 0..31
                float a1 = acc[2 + p][nt][r];     // conv2: rows 32..63
                float a2 = acc[4 + p][nt][r];     // conv3: rows 64..95
                float sg = 1.f / (1.f + __expf(-(a1 + bb2[p][r])));
                float o  = fmaxf(a0 + bb1[p][r] + sg + a2 + bb3[p][r], 0.f);
                int c = p * 16 + q4 * 4 + r;
                stash[c * 408 + ll * 8 + vv] = valid ? f2bf(o) : (unsigned short)0;
            }
        }
    }
    __syncthreads();

    // ---- store: coalesced 16B runs, 48 uint4 per channel ----
    for (int g = tid; g < 1536; g += 512) {
        int c = g / 48, sg = g % 48;
        uint4 val = *(const uint4*)&stash[c * 408 + sg * 8];
        *(uint4*)(xt + ((((size_t)n * 32 + c) * 64 + vblk) * 96 + th * 48) * 8 + sg * 8) = val;
    }
}

// ---------------------------------------------------------------------------
// hop: dst[b][w][l] = sum_v At[w][v] * src[b][v][l]   (bf16 MFMA 16x16x32)
// Block tile 128(w) x 96(l), K=512 in chunks of 32. 4 waves, 64x48 per wave.
// ---------------------------------------------------------------------------
__global__ __launch_bounds__(256)
void hop_kernel(const unsigned short* __restrict__ At,
                const unsigned short* __restrict__ src,
                unsigned short* __restrict__ dst)
{
    __shared__ unsigned short Ash[128 * 4 * 8];  // 8KB: [row][slot][8]
    __shared__ unsigned short Bsh[96 * 4 * 8];   // 6KB

    const int mtile = blockIdx.x;                // 0..3
    const int b = blockIdx.y;                    // 0..1023
    const int tid = threadIdx.x;
    const int lane = tid & 63, wv = tid >> 6;
    const int mhalf = (wv & 1) * 64, nhalf = (wv >> 1) * 48;
    const int col = lane & 15, q4 = lane >> 4;

    f32x4 acc[4][3];
    #pragma unroll
    for (int mt = 0; mt < 4; ++mt)
        #pragma unroll
        for (int nt = 0; nt < 3; ++nt)
            acc[mt][nt] = (f32x4){0.f, 0.f, 0.f, 0.f};

    const unsigned short* Abase = At + (size_t)(mtile * 128) * 512;
    const unsigned short* Bbase = src + (size_t)b * 64 * 96 * 8;

    for (int kc = 0; kc < 16; ++kc) {
        __syncthreads();
        #pragma unroll
        for (int t2 = 0; t2 < 2; ++t2) {
            int idx = tid + t2 * 256;
            int r = idx >> 2, q = idx & 3;
            uint4 val = *(const uint4*)(Abase + (size_t)r * 512 + kc * 32 + q * 8);
            *(uint4*)&Ash[(r * 4 + swz(r, q)) * 8] = val;
        }
        for (int g = tid; g < 384; g += 256) {
            int q = g / 96, l = g % 96;
            uint4 val = *(const uint4*)(Bbase + ((size_t)(kc * 4 + q) * 96 + l) * 8);
            *(uint4*)&Bsh[(l * 4 + swz(l, q)) * 8] = val;
        }
        __syncthreads();

        bf16x8 af[4], bfr[3];
        #pragma unroll
        for (int mt = 0; mt < 4; ++mt) {
            int r = mhalf + mt * 16 + col;
            af[mt] = *(const bf16x8*)&Ash[(r * 4 + swz(r, q4)) * 8];
        }
        #pragma unroll
        for (int nt = 0; nt < 3; ++nt) {
            int l = nhalf + nt * 16 + col;
            bfr[nt] = *(const bf16x8*)&Bsh[(l * 4 + swz(l, q4)) * 8];
        }
        #pragma unroll
        for (int mt = 0; mt < 4; ++mt)
            #pragma unroll
            for (int nt = 0; nt < 3; ++nt)
                acc[mt][nt] = __builtin_amdgcn_mfma_f32_16x16x32_bf16(
                    af[mt], bfr[nt], acc[mt][nt], 0, 0, 0);
    }

    // C/D layout: col = lane&15 (n=l), row = q4*4+reg (m=w). 4 regs = 4 consecutive w.
    #pragma unroll
    for (int mt = 0; mt < 4; ++mt) {
        int w0 = mtile * 128 + mhalf + mt * 16 + q4 * 4;
        int vblk = w0 >> 3, vv0 = w0 & 7;   // vv0 in {0,4}
        #pragma unroll
        for (int nt = 0; nt < 3; ++nt) {
            int l = nhalf + nt * 16 + col;
            uint2 u;
            u.x = (unsigned)f2bf(acc[mt][nt].x) | ((unsigned)f2bf(acc[mt][nt].y) << 16);
            u.y = (unsigned)f2bf(acc[mt][nt].z) | ((unsigned)f2bf(acc[mt][nt].w) << 16);
            *(uint2*)(dst + (((size_t)b * 64 + vblk) * 96 + l) * 8 + vv0) = u;
        }
    }
}

// ---------------------------------------------------------------------------
// proj: out[n][o][v][l] = PReLU(sum_c Wo[o][c]*h[c][v][l] + bout[o])
// h planes: c<32 -> xt, <64 -> x1, else x2. Block = (n, vblk, lq): 64 o x 128
// cols (col = vv*16 + ll so fp32 stores are 64B-contiguous in l).
// ---------------------------------------------------------------------------
__global__ __launch_bounds__(256)
void proj_kernel(const unsigned short* __restrict__ Wo,
                 const unsigned short* __restrict__ xt,
                 const unsigned short* __restrict__ x1,
                 const unsigned short* __restrict__ x2,
                 const float* __restrict__ bout,
                 const float* __restrict__ prelu_a,
                 float* __restrict__ out)
{
    __shared__ unsigned short WoSh[64 * 12 * 8]; // 12KB: [o][slot(12)][8]
    __shared__ unsigned short Bsh[128 * 4 * 8];  // 8KB:  [col][slot][8]

    const int lq = blockIdx.x;    // 0..5
    const int vblk = blockIdx.y;  // 0..62
    const int n = blockIdx.z;     // 0..31
    const int tid = threadIdx.x;
    const int lane = tid & 63, wv = tid >> 6;
    const int nbase = wv * 32;
    const int colL = lane & 15, q4 = lane >> 4;

    for (int g = tid; g < 768; g += 256) {
        int o = g / 12, slot = g % 12;
        int kc = slot >> 2, qq = slot & 3;
        uint4 val = *(const uint4*)(Wo + o * 96 + slot * 8);
        *(uint4*)&WoSh[(o * 12 + kc * 4 + swz(o, qq)) * 8] = val;
    }

    f32x4 acc[4][2];
    #pragma unroll
    for (int mt = 0; mt < 4; ++mt) { acc[mt][0] = (f32x4){0.f,0.f,0.f,0.f}; acc[mt][1] = (f32x4){0.f,0.f,0.f,0.f}; }

    const unsigned short* planes[3] = {xt, x1, x2};
    for (int kc = 0; kc < 3; ++kc) {
        __syncthreads();
        const unsigned short* P = planes[kc];
        // stage + transpose: 512 reads of 16B (c, ll, vv0..7) -> scatter to Bsh[col][c]
        #pragma unroll
        for (int t2 = 0; t2 < 2; ++t2) {
            int idx = tid + t2 * 256;
            int cl = idx >> 4, ll = idx & 15;     // c_local 0..31, ll 0..15
            union { uint4 u; unsigned short s[8]; } val;
            val.u = *(const uint4*)(P + (((size_t)(n * 32 + cl)) * 64 + vblk) * 96 * 8
                                      + (size_t)(lq * 16 + ll) * 8);
            int cq = cl >> 3, cw = cl & 7;
            #pragma unroll
            for (int vv = 0; vv < 8; ++vv) {
                int colv = vv * 16 + ll;
                Bsh[(colv * 4 + swz(colv, cq)) * 8 + cw] = val.s[vv];
            }
        }
        __syncthreads();

        bf16x8 af[4], bfr[2];
        #pragma unroll
        for (int mt = 0; mt < 4; ++mt) {
            int o = mt * 16 + colL;
            af[mt] = *(const bf16x8*)&WoSh[(o * 12 + kc * 4 + swz(o, q4)) * 8];
        }
        #pragma unroll
        for (int nt = 0; nt < 2; ++nt) {
            int colv = nbase + nt * 16 + colL;
            bfr[nt] = *(const bf16x8*)&Bsh[(colv * 4 + swz(colv, q4)) * 8];
        }
        #pragma unroll
        for (int mt = 0; mt < 4; ++mt)
            #pragma unroll
            for (int nt = 0; nt < 2; ++nt)
                acc[mt][nt] = __builtin_amdgcn_mfma_f32_16x16x32_bf16(
                    af[mt], bfr[nt], acc[mt][nt], 0, 0, 0);
    }

    const float pa = prelu_a[0];
    #pragma unroll
    for (int mt = 0; mt < 4; ++mt) {
        #pragma unroll
        for (int nt = 0; nt < 2; ++nt) {
            #pragma unroll
            for (int r = 0; r < 4; ++r) {
                int o = mt * 16 + q4 * 4 + r;
                int colv = nbase + nt * 16 + colL;
                int vv = colv >> 4, ll = colv & 15;
                int v = vblk * 8 + vv, l = lq * 16 + ll;
                if (v < 500 && l < 94) {
                    float val = acc[mt][nt][r] + bout[o];
                    val = (val > 0.f) ? val : pa * val;
                    out[(((size_t)n * 64 + o) * 500 + v) * 94 + l] = val;
                }
            }
        }
    }
}

// ---------------------------------------------------------------------------
extern "C" void kernel_launch(void* const* d_in, const int* in_sizes, int n_in,
                              void* d_out, int out_size, void* d_ws, size_t ws_size,
                              hipStream_t stream)
{
    const float* x    = (const float*)d_in[0];
    const float* A    = (const float*)d_in[1];
    const float* w1   = (const float*)d_in[2];
    const float* b1   = (const float*)d_in[3];
    const float* w2   = (const float*)d_in[4];
    const float* b2   = (const float*)d_in[5];
    const float* w3   = (const float*)d_in[6];
    const float* b3   = (const float*)d_in[7];
    const float* wout = (const float*)d_in[8];
    const float* bout = (const float*)d_in[9];
    const float* pa   = (const float*)d_in[10];
    float* out = (float*)d_out;

    char* ws = (char*)d_ws;
    unsigned short* xt = (unsigned short*)(ws);
    unsigned short* x1 = (unsigned short*)(ws + WS_S);
    unsigned short* x2 = (unsigned short*)(ws + 2 * WS_S);
    unsigned short* At = (unsigned short*)(ws + 3 * WS_S);
    unsigned short* Wa = (unsigned short*)(ws + 3 * WS_S + AT_B);
    unsigned short* Wo = (unsigned short*)(ws + 3 * WS_S + AT_B + WA_B);

    const int prep_elems = 512 * 512 + 3 * 3 * 32 * 32 + 64 * 96;
    prep_kernel<<<dim3((prep_elems + 255) / 256), 256, 0, stream>>>(
        A, w1, w2, w3, wout, At, Wa, Wo);
    conv_kernel<<<dim3(2, 63, 32), 512, 0, stream>>>(x, Wa, b1, b2, b3, xt);
    hop_kernel<<<dim3(4, 1024), 256, 0, stream>>>(At, xt, x1);
    hop_kernel<<<dim3(4, 1024), 256, 0, stream>>>(At, x1, x2);
    proj_kernel<<<dim3(6, 63, 32), 256, 0, stream>>>(Wo, xt, x1, x2, bout, pa, out);
}

// Round 4
// 922.930 us; speedup vs baseline: 1.1249x; 1.1249x over previous
//
#include <hip/hip_runtime.h>
#include <stdint.h>

// ---------------------------------------------------------------------------
// STGTCN layer: xt = relu(conv1(x)+b1 + sigmoid(conv2(x)+b2) + conv3(x)+b3)
//               x1 = A^T xt (over V), x2 = A^T x1
//               out = PReLU(W_out · concat(xt,x1,x2) + b_out)
// N=32, C=32, V=500 (pad 512), T=96 -> T'=94 (pad 96), C_OUT=64, GC=96
//
// Workspace layout (bf16 h-planes stored as [b=n*32+c][vblk=v/8][l(96)][v%8]
// so that MFMA B-fragments (k = v, 8-contiguous per lane) are 16B groups):
//   xt : S bytes       x1 : S       x2 : S       (S = 1024*64*96*8*2)
//   At : 512*512 bf16 (A^T, zero-padded => no masking in GEMMs)
//   Wa : conv weights bf16 repacked [koff][conv*32+co][ci]  (MFMA A-operand)
//   Wo : w_out bf16 [o][c]
// ---------------------------------------------------------------------------

typedef float  f32x4  __attribute__((ext_vector_type(4)));
typedef float  f32x2  __attribute__((ext_vector_type(2)));
typedef short  bf16x8 __attribute__((ext_vector_type(8)));

static __device__ __forceinline__ unsigned short f2bf(float f) {
    union { float f; unsigned u; } v; v.f = f;
    unsigned u = v.u;
    return (unsigned short)((u + 0x7fffu + ((u >> 16) & 1u)) >> 16);  // RTNE
}

#define WS_S   ((size_t)1024 * 64 * 96 * 8 * 2)   // one bf16 h-plane set
#define AT_B   (512u * 512u * 2u)
#define WA_B   (3u * 96u * 32u * 2u)              // 18KB bf16 conv weights

// swizzle of 16B k-slots within a 64B LDS row (kills frag-read bank conflicts)
static __device__ __forceinline__ int swz(int row, int q) {
    return q ^ (row & 3) ^ ((row >> 2) & 3);
}

// ---------------------------------------------------------------------------
// prep: build At (bf16, transposed, zero-padded), Wa (bf16 repack), Wo (bf16)
// ---------------------------------------------------------------------------
__global__ __launch_bounds__(256)
void prep_kernel(const float* __restrict__ A,
                 const float* __restrict__ w1, const float* __restrict__ w2,
                 const float* __restrict__ w3, const float* __restrict__ wout,
                 unsigned short* __restrict__ At, unsigned short* __restrict__ Wa,
                 unsigned short* __restrict__ Wo)
{
    int idx = blockIdx.x * 256 + threadIdx.x;
    if (idx < 512 * 512) {
        int w = idx >> 9, v = idx & 511;
        float val = (w < 500 && v < 500) ? A[v * 500 + w] : 0.f;  // At[w][v] = A[v][w]
        At[idx] = f2bf(val);
    } else if (idx < 512 * 512 + 3 * 3 * 32 * 32) {
        // Wa[t], t = ((koff*3 + conv)*32 + co)*32 + ci  ->  w_conv[co][ci][0][koff]
        int t = idx - 512 * 512;
        int ci = t & 31;
        int co = (t >> 5) & 31;
        int rc = t >> 10;            // koff*3 + conv
        int conv = rc % 3, koff = rc / 3;
        const float* ws = (conv == 0) ? w1 : ((conv == 1) ? w2 : w3);
        Wa[t] = f2bf(ws[co * 96 + ci * 3 + koff]);
    } else if (idx < 512 * 512 + 3 * 3 * 32 * 32 + 64 * 96) {
        int t = idx - (512 * 512 + 3 * 3 * 32 * 32);
        Wo[t] = f2bf(wout[t]);
    }
}

// ---------------------------------------------------------------------------
// conv (MFMA version): per block = (t-half th, vblk, n).
// GEMM: out[row = conv*32+co][col = ll*8+vv] = sum_ci Wa[koff][row][ci] *
//       X[ci][th*48+ll+koff][vv], accumulated over koff=0..2.
// M=96 (3convs x 32c), N=384 (48 l x 8 vv), K=32 per tap (one 16x16x32 MFMA).
// 8 waves, each owns 48 cols (3 n-tiles), all 6 m-tiles; A-frags in registers.
// ---------------------------------------------------------------------------
__global__ __launch_bounds__(512, 1)
void conv_kernel(const float* __restrict__ x, const unsigned short* __restrict__ Wa,
                 const float* __restrict__ b1, const float* __restrict__ b2,
                 const float* __restrict__ b3, unsigned short* __restrict__ xt)
{
    __shared__ unsigned short Xs2[52 * 256];    // [tl][vv][ci] bf16, 26.6KB
    __shared__ unsigned short WaSh[9216];       // [koff][conv*32+co][ci], 18KB
    __shared__ unsigned short stash[32 * 408];  // [co][ll*8+vv] (stride 408 = pad), 26.1KB

    const int th   = blockIdx.x;    // 0..1 (t-half: cols l = th*48 .. th*48+47)
    const int vblk = blockIdx.y;    // 0..62
    const int n    = blockIdx.z;    // 0..31
    const int tid  = threadIdx.x;
    const int lane = tid & 63, wv = tid >> 6;
    const int cl = lane & 15, q4 = lane >> 4;
    const int nbase = wv * 48;

    // ---- stage Wa (18KB, coalesced 16B) ----
    for (int g = tid; g < 1152; g += 512)
        *(uint4*)&WaSh[g * 8] = *(const uint4*)(Wa + g * 8);

    // ---- stage + transpose x tile -> Xs2[tl][vv][ci] ----
    for (int s = 0; s < 2; ++s) {
        int fid = tid + s * 512;
        if (fid < 832) {
            int rq = fid / 13, seg = fid % 13;
            int vv = rq & 7, i4 = rq >> 3;
            int v = vblk * 8 + vv;
            int tbase = th * 48 + seg * 4;
            float b[4][4];
            #pragma unroll
            for (int di = 0; di < 4; ++di) {
                float4 f = make_float4(0.f, 0.f, 0.f, 0.f);
                if (v < 500 && tbase < 96)
                    f = *(const float4*)(x + (((size_t)n * 32 + i4 * 4 + di) * 500 + v) * 96 + tbase);
                b[di][0] = f.x; b[di][1] = f.y; b[di][2] = f.z; b[di][3] = f.w;
            }
            #pragma unroll
            for (int j = 0; j < 4; ++j) {
                uint2 u;
                u.x = (unsigned)f2bf(b[0][j]) | ((unsigned)f2bf(b[1][j]) << 16);
                u.y = (unsigned)f2bf(b[2][j]) | ((unsigned)f2bf(b[3][j]) << 16);
                *(uint2*)&Xs2[(seg * 4 + j) * 256 + vv * 32 + i4 * 4] = u;
            }
        }
    }

    // bias preload (per-lane c's; L1/L2-hot)
    float bb1[2][4], bb2[2][4], bb3[2][4];
    #pragma unroll
    for (int p = 0; p < 2; ++p)
        #pragma unroll
        for (int r = 0; r < 4; ++r) {
            int c = p * 16 + q4 * 4 + r;
            bb1[p][r] = b1[c]; bb2[p][r] = b2[c]; bb3[p][r] = b3[c];
        }

    __syncthreads();

    // ---- A-fragments resident in registers: 6 m-tiles x 3 taps ----
    bf16x8 af[6][3];
    #pragma unroll
    for (int mt = 0; mt < 6; ++mt)
        #pragma unroll
        for (int ko = 0; ko < 3; ++ko)
            af[mt][ko] = *(const bf16x8*)&WaSh[ko * 3072 + (mt * 16 + cl) * 32 + q4 * 8];

    f32x4 acc[6][3];
    #pragma unroll
    for (int mt = 0; mt < 6; ++mt)
        #pragma unroll
        for (int nt = 0; nt < 3; ++nt)
            acc[mt][nt] = (f32x4){0.f, 0.f, 0.f, 0.f};

    // ---- main: 9 B-frag reads, 54 MFMAs, no K-loop ----
    #pragma unroll
    for (int ko = 0; ko < 3; ++ko) {
        #pragma unroll
        for (int nt = 0; nt < 3; ++nt) {
            int col = nbase + nt * 16 + cl;
            int ll = col >> 3, vv = col & 7;
            bf16x8 bf = *(const bf16x8*)&Xs2[(ll + ko) * 256 + vv * 32 + q4 * 8];
            #pragma unroll
            for (int mt = 0; mt < 6; ++mt)
                acc[mt][nt] = __builtin_amdgcn_mfma_f32_16x16x32_bf16(
                    af[mt][ko], bf, acc[mt][nt], 0, 0, 0);
        }
    }

    // ---- epilogue: rows (c, 32+c, 64+c) live in same lane, same reg r ----
    #pragma unroll
    for (int p = 0; p < 2; ++p) {
        #pragma unroll
        for (int nt = 0; nt < 3; ++nt) {
            int col = nbase + nt * 16 + cl;
            int ll = col >> 3, vv = col & 7;
            bool valid = (th * 48 + ll) < 94;
            #pragma unroll
            for (int r = 0; r < 4; ++r) {
                float a0 = acc[p][nt][r];         // conv1: rows 0..31
                float a1 = acc[2 + p][nt][r];     // conv2: rows 32..63
                float a2 = acc[4 + p][nt][r];     // conv3: rows 64..95
                float sg = 1.f / (1.f + __expf(-(a1 + bb2[p][r])));
                float o  = fmaxf(a0 + bb1[p][r] + sg + a2 + bb3[p][r], 0.f);
                int c = p * 16 + q4 * 4 + r;
                stash[c * 408 + ll * 8 + vv] = valid ? f2bf(o) : (unsigned short)0;
            }
        }
    }
    __syncthreads();

    // ---- store: coalesced 16B runs, 48 uint4 per channel ----
    for (int g = tid; g < 1536; g += 512) {
        int c = g / 48, sg = g % 48;
        uint4 val = *(const uint4*)&stash[c * 408 + sg * 8];
        *(uint4*)(xt + ((((size_t)n * 32 + c) * 64 + vblk) * 96 + th * 48) * 8 + sg * 8) = val;
    }
}

// ---------------------------------------------------------------------------
// hop: dst[b][w][l] = sum_v At[w][v] * src[b][v][l]   (bf16 MFMA 16x16x32)
// Block tile 128(w) x 96(l), K=512 in chunks of 32. 4 waves, 64x48 per wave.
// 1D grid with XCD-aware mapping: the 4 mtile-blocks sharing b run
// back-to-back on the SAME XCD so the src[b] slice (98KB) is L2-hot for
// blocks 2..4 instead of being fetched by 4 different XCDs.
// ---------------------------------------------------------------------------
__global__ __launch_bounds__(256)
void hop_kernel(const unsigned short* __restrict__ At,
                const unsigned short* __restrict__ src,
                unsigned short* __restrict__ dst)
{
    __shared__ unsigned short Ash[128 * 4 * 8];  // 8KB: [row][slot][8]
    __shared__ unsigned short Bsh[96 * 4 * 8];   // 6KB

    const int bid = blockIdx.x;                  // 0..4095
    const int xcd = bid & 7;                     // dispatch round-robins XCDs
    const int s = bid >> 3;                      // 0..511 per-XCD sequence
    const int mtile = s & 3;                     // mtile fastest within XCD
    const int b = xcd * 128 + (s >> 2);          // each XCD owns 128 b's
    const int tid = threadIdx.x;
    const int lane = tid & 63, wv = tid >> 6;
    const int mhalf = (wv & 1) * 64, nhalf = (wv >> 1) * 48;
    const int col = lane & 15, q4 = lane >> 4;

    f32x4 acc[4][3];
    #pragma unroll
    for (int mt = 0; mt < 4; ++mt)
        #pragma unroll
        for (int nt = 0; nt < 3; ++nt)
            acc[mt][nt] = (f32x4){0.f, 0.f, 0.f, 0.f};

    const unsigned short* Abase = At + (size_t)(mtile * 128) * 512;
    const unsigned short* Bbase = src + (size_t)b * 64 * 96 * 8;

    for (int kc = 0; kc < 16; ++kc) {
        __syncthreads();
        #pragma unroll
        for (int t2 = 0; t2 < 2; ++t2) {
            int idx = tid + t2 * 256;
            int r = idx >> 2, q = idx & 3;
            uint4 val = *(const uint4*)(Abase + (size_t)r * 512 + kc * 32 + q * 8);
            *(uint4*)&Ash[(r * 4 + swz(r, q)) * 8] = val;
        }
        for (int g = tid; g < 384; g += 256) {
            int q = g / 96, l = g % 96;
            uint4 val = *(const uint4*)(Bbase + ((size_t)(kc * 4 + q) * 96 + l) * 8);
            *(uint4*)&Bsh[(l * 4 + swz(l, q)) * 8] = val;
        }
        __syncthreads();

        bf16x8 af[4], bfr[3];
        #pragma unroll
        for (int mt = 0; mt < 4; ++mt) {
            int r = mhalf + mt * 16 + col;
            af[mt] = *(const bf16x8*)&Ash[(r * 4 + swz(r, q4)) * 8];
        }
        #pragma unroll
        for (int nt = 0; nt < 3; ++nt) {
            int l = nhalf + nt * 16 + col;
            bfr[nt] = *(const bf16x8*)&Bsh[(l * 4 + swz(l, q4)) * 8];
        }
        #pragma unroll
        for (int mt = 0; mt < 4; ++mt)
            #pragma unroll
            for (int nt = 0; nt < 3; ++nt)
                acc[mt][nt] = __builtin_amdgcn_mfma_f32_16x16x32_bf16(
                    af[mt], bfr[nt], acc[mt][nt], 0, 0, 0);
    }

    // C/D layout: col = lane&15 (n=l), row = q4*4+reg (m=w). 4 regs = 4 consecutive w.
    #pragma unroll
    for (int mt = 0; mt < 4; ++mt) {
        int w0 = mtile * 128 + mhalf + mt * 16 + q4 * 4;
        int vblk = w0 >> 3, vv0 = w0 & 7;   // vv0 in {0,4}
        #pragma unroll
        for (int nt = 0; nt < 3; ++nt) {
            int l = nhalf + nt * 16 + col;
            uint2 u;
            u.x = (unsigned)f2bf(acc[mt][nt].x) | ((unsigned)f2bf(acc[mt][nt].y) << 16);
            u.y = (unsigned)f2bf(acc[mt][nt].z) | ((unsigned)f2bf(acc[mt][nt].w) << 16);
            *(uint2*)(dst + (((size_t)b * 64 + vblk) * 96 + l) * 8 + vv0) = u;
        }
    }
}

// ---------------------------------------------------------------------------
// proj v2: out[n][o][v][l] = PReLU(sum_c Wo[o][c]*h[c][v][l] + bout[o])
// h planes: c<32 -> xt, <64 -> x1, else x2.
// Block = (vblk, n), 512 threads / 8 waves. Wave wv owns vv = wv, all 96 l.
// col = vv*96 + l  ->  each (o,v) output row's 6x64B segments are stored
// back-to-back by the same lanes => full-line L2 merges, no cross-block RMW
// (old version: 6 different blocks each wrote 64B of a 376B row => 1.35x
// write amplification + RMW fetches, 2.5 TB/s).
// ---------------------------------------------------------------------------
__global__ __launch_bounds__(512, 1)
void proj_kernel(const unsigned short* __restrict__ Wo,
                 const unsigned short* __restrict__ xt,
                 const unsigned short* __restrict__ x1,
                 const unsigned short* __restrict__ x2,
                 const float* __restrict__ bout,
                 const float* __restrict__ prelu_a,
                 float* __restrict__ out)
{
    __shared__ unsigned short WoSh[64 * 12 * 8]; // 12KB: [o][slot(12)][8]
    __shared__ unsigned short Bsh[768 * 4 * 8];  // 48KB: [col=vv*96+l][slot][8]

    const int vblk = blockIdx.x;  // 0..62
    const int n = blockIdx.y;     // 0..31
    const int tid = threadIdx.x;
    const int lane = tid & 63, wv = tid >> 6;   // wv = vv owned by this wave
    const int colL = lane & 15, q4 = lane >> 4;

    for (int g = tid; g < 768; g += 512) {
        int o = g / 12, slot = g % 12;
        int kc = slot >> 2, qq = slot & 3;
        uint4 val = *(const uint4*)(Wo + o * 96 + slot * 8);
        *(uint4*)&WoSh[(o * 12 + kc * 4 + swz(o, qq)) * 8] = val;
    }

    f32x4 acc[4][6];
    #pragma unroll
    for (int mt = 0; mt < 4; ++mt)
        #pragma unroll
        for (int nt = 0; nt < 6; ++nt)
            acc[mt][nt] = (f32x4){0.f, 0.f, 0.f, 0.f};

    const unsigned short* planes[3] = {xt, x1, x2};
    for (int kc = 0; kc < 3; ++kc) {
        __syncthreads();
        const unsigned short* P = planes[kc];
        // stage + transpose one full plane slice [32c][96l][8vv] -> Bsh[col][c]
        // 3072 uint4 loads (coalesced: consecutive tid = consecutive l)
        #pragma unroll
        for (int s = 0; s < 6; ++s) {
            int idx = tid + s * 512;              // 0..3071
            int cl = idx / 96, l = idx % 96;      // c_local 0..31, l 0..95
            union { uint4 u; unsigned short sh[8]; } val;
            val.u = *(const uint4*)(P + (((size_t)(n * 32 + cl)) * 64 + vblk) * 96 * 8
                                      + (size_t)l * 8);
            int cq = cl >> 3, cw = cl & 7;
            #pragma unroll
            for (int vv = 0; vv < 8; ++vv) {
                int colv = vv * 96 + l;
                Bsh[(colv * 4 + swz(colv, cq)) * 8 + cw] = val.sh[vv];
            }
        }
        __syncthreads();

        bf16x8 af[4], bfr[6];
        #pragma unroll
        for (int mt = 0; mt < 4; ++mt) {
            int o = mt * 16 + colL;
            af[mt] = *(const bf16x8*)&WoSh[(o * 12 + kc * 4 + swz(o, q4)) * 8];
        }
        #pragma unroll
        for (int nt = 0; nt < 6; ++nt) {
            int colv = wv * 96 + nt * 16 + colL;
            bfr[nt] = *(const bf16x8*)&Bsh[(colv * 4 + swz(colv, q4)) * 8];
        }
        #pragma unroll
        for (int mt = 0; mt < 4; ++mt)
            #pragma unroll
            for (int nt = 0; nt < 6; ++nt)
                acc[mt][nt] = __builtin_amdgcn_mfma_f32_16x16x32_bf16(
                    af[mt], bfr[nt], acc[mt][nt], 0, 0, 0);
    }

    const float pa = prelu_a[0];
    const int v = vblk * 8 + wv;
    if (v < 500) {
        #pragma unroll
        for (int mt = 0; mt < 4; ++mt) {
            #pragma unroll
            for (int r = 0; r < 4; ++r) {
                int o = mt * 16 + q4 * 4 + r;
                float bo = bout[o];
                float* orow = out + (((size_t)n * 64 + o) * 500 + v) * 94;
                #pragma unroll
                for (int nt = 0; nt < 6; ++nt) {
                    int l = nt * 16 + colL;
                    if (l < 94) {
                        float val = acc[mt][nt][r] + bo;
                        val = (val > 0.f) ? val : pa * val;
                        orow[l] = val;
                    }
                }
            }
        }
    }
}

// ---------------------------------------------------------------------------
extern "C" void kernel_launch(void* const* d_in, const int* in_sizes, int n_in,
                              void* d_out, int out_size, void* d_ws, size_t ws_size,
                              hipStream_t stream)
{
    const float* x    = (const float*)d_in[0];
    const float* A    = (const float*)d_in[1];
    const float* w1   = (const float*)d_in[2];
    const float* b1   = (const float*)d_in[3];
    const float* w2   = (const float*)d_in[4];
    const float* b2   = (const float*)d_in[5];
    const float* w3   = (const float*)d_in[6];
    const float* b3   = (const float*)d_in[7];
    const float* wout = (const float*)d_in[8];
    const float* bout = (const float*)d_in[9];
    const float* pa   = (const float*)d_in[10];
    float* out = (float*)d_out;

    char* ws = (char*)d_ws;
    unsigned short* xt = (unsigned short*)(ws);
    unsigned short* x1 = (unsigned short*)(ws + WS_S);
    unsigned short* x2 = (unsigned short*)(ws + 2 * WS_S);
    unsigned short* At = (unsigned short*)(ws + 3 * WS_S);
    unsigned short* Wa = (unsigned short*)(ws + 3 * WS_S + AT_B);
    unsigned short* Wo = (unsigned short*)(ws + 3 * WS_S + AT_B + WA_B);

    const int prep_elems = 512 * 512 + 3 * 3 * 32 * 32 + 64 * 96;
    prep_kernel<<<dim3((prep_elems + 255) / 256), 256, 0, stream>>>(
        A, w1, w2, w3, wout, At, Wa, Wo);
    conv_kernel<<<dim3(2, 63, 32), 512, 0, stream>>>(x, Wa, b1, b2, b3, xt);
    hop_kernel<<<dim3(4096), 256, 0, stream>>>(At, xt, x1);
    hop_kernel<<<dim3(4096), 256, 0, stream>>>(At, x1, x2);
    proj_kernel<<<dim3(63, 32), 512, 0, stream>>>(Wo, xt, x1, x2, bout, pa, out);
}

// Round 5
// 840.325 us; speedup vs baseline: 1.2355x; 1.0983x over previous
//
#include <hip/hip_runtime.h>
#include <stdint.h>

// ---------------------------------------------------------------------------
// STGTCN layer: xt = relu(conv1(x)+b1 + sigmoid(conv2(x)+b2) + conv3(x)+b3)
//               x1 = A^T xt (over V), x2 = A^T x1
//               out = PReLU(W_out · concat(xt,x1,x2) + b_out)
// N=32, C=32, V=500 (pad 512), T=96 -> T'=94 (pad 96), C_OUT=64, GC=96
//
// Workspace layout (bf16 h-planes stored as [b=n*32+c][vblk=v/8][l(96)][v%8]
// so that MFMA B-fragments (k = v, 8-contiguous per lane) are 16B groups):
//   xt : S bytes       x1 : S       x2 : S       (S = 1024*64*96*8*2)
//   At_fr : 512KB bf16 A^T in MFMA-fragment-major layout
//           [rg(32)][kc32(16)][q4(4)][col(16)][8]  = A[v=kc*32+q4*8+e][w=rg*16+col]
//           (zero-padded; a wave's A-frag load = one coalesced 1KB global read)
//   Wa : conv weights bf16 repacked [koff][conv*32+co][ci]  (MFMA A-operand)
//   Wo : w_out bf16 [o][c]
// ---------------------------------------------------------------------------

typedef float  f32x4  __attribute__((ext_vector_type(4)));
typedef float  f32x2  __attribute__((ext_vector_type(2)));
typedef short  bf16x8 __attribute__((ext_vector_type(8)));

static __device__ __forceinline__ unsigned short f2bf(float f) {
    union { float f; unsigned u; } v; v.f = f;
    unsigned u = v.u;
    return (unsigned short)((u + 0x7fffu + ((u >> 16) & 1u)) >> 16);  // RTNE
}

#define WS_S   ((size_t)1024 * 64 * 96 * 8 * 2)   // one bf16 h-plane set
#define AT_B   (512u * 512u * 2u)
#define WA_B   (3u * 96u * 32u * 2u)              // 18KB bf16 conv weights

// swizzle of 16B k-slots within a 64B LDS row (kills frag-read bank conflicts)
static __device__ __forceinline__ int swz(int row, int q) {
    return q ^ (row & 3) ^ ((row >> 2) & 3);
}
// 8-slot variant for 128B LDS rows (hop B-tile): 2-way max on reads/writes
static __device__ __forceinline__ int swz8(int row, int q) {
    return q ^ (row & 7);
}

// ---------------------------------------------------------------------------
// prep: build At_fr (bf16 fragment-major A^T), Wa (bf16 repack), Wo (bf16)
// ---------------------------------------------------------------------------
__global__ __launch_bounds__(256)
void prep_kernel(const float* __restrict__ A,
                 const float* __restrict__ w1, const float* __restrict__ w2,
                 const float* __restrict__ w3, const float* __restrict__ wout,
                 unsigned short* __restrict__ At, unsigned short* __restrict__ Wa,
                 unsigned short* __restrict__ Wo)
{
    int idx = blockIdx.x * 256 + threadIdx.x;
    if (idx < 512 * 512) {
        // t = ((rg*16 + kc)*4 + q4)*128 + col*8 + e
        int t = idx;
        int e   = t & 7;
        int col = (t >> 3) & 15;
        int q4  = (t >> 7) & 3;
        int kc  = (t >> 9) & 15;
        int rg  = t >> 13;
        int w = rg * 16 + col;          // output row (m of the hop GEMM)
        int v = kc * 32 + q4 * 8 + e;   // k
        float val = (w < 500 && v < 500) ? A[v * 500 + w] : 0.f;  // At[w][v] = A[v][w]
        At[idx] = f2bf(val);
    } else if (idx < 512 * 512 + 3 * 3 * 32 * 32) {
        // Wa[t], t = ((koff*3 + conv)*32 + co)*32 + ci  ->  w_conv[co][ci][0][koff]
        int t = idx - 512 * 512;
        int ci = t & 31;
        int co = (t >> 5) & 31;
        int rc = t >> 10;            // koff*3 + conv
        int conv = rc % 3, koff = rc / 3;
        const float* ws = (conv == 0) ? w1 : ((conv == 1) ? w2 : w3);
        Wa[t] = f2bf(ws[co * 96 + ci * 3 + koff]);
    } else if (idx < 512 * 512 + 3 * 3 * 32 * 32 + 64 * 96) {
        int t = idx - (512 * 512 + 3 * 3 * 32 * 32);
        Wo[t] = f2bf(wout[t]);
    }
}

// ---------------------------------------------------------------------------
// conv (MFMA version): per block = (t-half th, vblk, n).
// GEMM: out[row = conv*32+co][col = ll*8+vv] = sum_ci Wa[koff][row][ci] *
//       X[ci][th*48+ll+koff][vv], accumulated over koff=0..2.
// M=96 (3convs x 32c), N=384 (48 l x 8 vv), K=32 per tap (one 16x16x32 MFMA).
// 8 waves, each owns 48 cols (3 n-tiles), all 6 m-tiles; A-frags in registers.
// ---------------------------------------------------------------------------
__global__ __launch_bounds__(512, 1)
void conv_kernel(const float* __restrict__ x, const unsigned short* __restrict__ Wa,
                 const float* __restrict__ b1, const float* __restrict__ b2,
                 const float* __restrict__ b3, unsigned short* __restrict__ xt)
{
    __shared__ unsigned short Xs2[52 * 256];    // [tl][vv][ci] bf16, 26.6KB
    __shared__ unsigned short WaSh[9216];       // [koff][conv*32+co][ci], 18KB
    __shared__ unsigned short stash[32 * 408];  // [co][ll*8+vv] (stride 408 = pad), 26.1KB

    const int th   = blockIdx.x;    // 0..1 (t-half: cols l = th*48 .. th*48+47)
    const int vblk = blockIdx.y;    // 0..62
    const int n    = blockIdx.z;    // 0..31
    const int tid  = threadIdx.x;
    const int lane = tid & 63, wv = tid >> 6;
    const int cl = lane & 15, q4 = lane >> 4;
    const int nbase = wv * 48;

    // ---- stage Wa (18KB, coalesced 16B) ----
    for (int g = tid; g < 1152; g += 512)
        *(uint4*)&WaSh[g * 8] = *(const uint4*)(Wa + g * 8);

    // ---- stage + transpose x tile -> Xs2[tl][vv][ci] ----
    for (int s = 0; s < 2; ++s) {
        int fid = tid + s * 512;
        if (fid < 832) {
            int rq = fid / 13, seg = fid % 13;
            int vv = rq & 7, i4 = rq >> 3;
            int v = vblk * 8 + vv;
            int tbase = th * 48 + seg * 4;
            float b[4][4];
            #pragma unroll
            for (int di = 0; di < 4; ++di) {
                float4 f = make_float4(0.f, 0.f, 0.f, 0.f);
                if (v < 500 && tbase < 96)
                    f = *(const float4*)(x + (((size_t)n * 32 + i4 * 4 + di) * 500 + v) * 96 + tbase);
                b[di][0] = f.x; b[di][1] = f.y; b[di][2] = f.z; b[di][3] = f.w;
            }
            #pragma unroll
            for (int j = 0; j < 4; ++j) {
                uint2 u;
                u.x = (unsigned)f2bf(b[0][j]) | ((unsigned)f2bf(b[1][j]) << 16);
                u.y = (unsigned)f2bf(b[2][j]) | ((unsigned)f2bf(b[3][j]) << 16);
                *(uint2*)&Xs2[(seg * 4 + j) * 256 + vv * 32 + i4 * 4] = u;
            }
        }
    }

    // bias preload (per-lane c's; L1/L2-hot)
    float bb1[2][4], bb2[2][4], bb3[2][4];
    #pragma unroll
    for (int p = 0; p < 2; ++p)
        #pragma unroll
        for (int r = 0; r < 4; ++r) {
            int c = p * 16 + q4 * 4 + r;
            bb1[p][r] = b1[c]; bb2[p][r] = b2[c]; bb3[p][r] = b3[c];
        }

    __syncthreads();

    // ---- A-fragments resident in registers: 6 m-tiles x 3 taps ----
    bf16x8 af[6][3];
    #pragma unroll
    for (int mt = 0; mt < 6; ++mt)
        #pragma unroll
        for (int ko = 0; ko < 3; ++ko)
            af[mt][ko] = *(const bf16x8*)&WaSh[ko * 3072 + (mt * 16 + cl) * 32 + q4 * 8];

    f32x4 acc[6][3];
    #pragma unroll
    for (int mt = 0; mt < 6; ++mt)
        #pragma unroll
        for (int nt = 0; nt < 3; ++nt)
            acc[mt][nt] = (f32x4){0.f, 0.f, 0.f, 0.f};

    // ---- main: 9 B-frag reads, 54 MFMAs, no K-loop ----
    #pragma unroll
    for (int ko = 0; ko < 3; ++ko) {
        #pragma unroll
        for (int nt = 0; nt < 3; ++nt) {
            int col = nbase + nt * 16 + cl;
            int ll = col >> 3, vv = col & 7;
            bf16x8 bf = *(const bf16x8*)&Xs2[(ll + ko) * 256 + vv * 32 + q4 * 8];
            #pragma unroll
            for (int mt = 0; mt < 6; ++mt)
                acc[mt][nt] = __builtin_amdgcn_mfma_f32_16x16x32_bf16(
                    af[mt][ko], bf, acc[mt][nt], 0, 0, 0);
        }
    }

    // ---- epilogue: rows (c, 32+c, 64+c) live in same lane, same reg r ----
    #pragma unroll
    for (int p = 0; p < 2; ++p) {
        #pragma unroll
        for (int nt = 0; nt < 3; ++nt) {
            int col = nbase + nt * 16 + cl;
            int ll = col >> 3, vv = col & 7;
            bool valid = (th * 48 + ll) < 94;
            #pragma unroll
            for (int r = 0; r < 4; ++r) {
                float a0 = acc[p][nt][r];         // conv1: rows 0..31
                float a1 = acc[2 + p][nt][r];     // conv2: rows 32..63
                float a2 = acc[4 + p][nt][r];     // conv3: rows 64..95
                float sg = 1.f / (1.f + __expf(-(a1 + bb2[p][r])));
                float o  = fmaxf(a0 + bb1[p][r] + sg + a2 + bb3[p][r], 0.f);
                int c = p * 16 + q4 * 4 + r;
                stash[c * 408 + ll * 8 + vv] = valid ? f2bf(o) : (unsigned short)0;
            }
        }
    }
    __syncthreads();

    // ---- store: coalesced 16B runs, 48 uint4 per channel ----
    for (int g = tid; g < 1536; g += 512) {
        int c = g / 48, sg = g % 48;
        uint4 val = *(const uint4*)&stash[c * 408 + sg * 8];
        *(uint4*)(xt + ((((size_t)n * 32 + c) * 64 + vblk) * 96 + th * 48) * 8 + sg * 8) = val;
    }
}

// ---------------------------------------------------------------------------
// hop v2: dst[b][w][l] = sum_v At[w][v] * src[b][v][l]   (bf16 MFMA 16x16x32)
// Block = (mtile, b-pair): tile 128(w) x 192(2b x 96l), K=512 in chunks of 64.
// 4 waves: wave (wv&1 -> m-half of 64, wv>>1 -> which b). 24 acc tiles/wave.
// A-operand read DIRECTLY from L2-resident At_fr (fragment-major, 1KB
// coalesced per wave) -- no LDS, no staging, no barrier for A.
// B staged in LDS with 8-slot XOR swizzle (2-way max bank access).
// 8 phases x 2 barriers (vs 16 x 2 before), 48 MFMAs/wave/phase (vs 12).
// XCD-aware: all 4 mtiles of a b-pair-group run on the same XCD.
// ---------------------------------------------------------------------------
__global__ __launch_bounds__(256)
void hop_kernel(const unsigned short* __restrict__ At_fr,
                const unsigned short* __restrict__ src,
                unsigned short* __restrict__ dst)
{
    __shared__ unsigned short Bsh[2 * 96 * 8 * 8];  // 24KB: [bs][l][slot8][8]

    const int bid = blockIdx.x;                  // 0..2047
    const int xcd = bid & 7;
    const int s = bid >> 3;                      // 0..255 per-XCD sequence
    const int mtile = s & 3;
    const int bp = xcd * 64 + (s >> 2);          // b-pair 0..511
    const int b0 = bp * 2;
    const int tid = threadIdx.x;
    const int lane = tid & 63, wv = tid >> 6;
    const int mhalf = (wv & 1) * 64;
    const int bsel = wv >> 1;                    // which b of the pair
    const int col = lane & 15, q4 = lane >> 4;

    f32x4 acc[4][6];
    #pragma unroll
    for (int mt = 0; mt < 4; ++mt)
        #pragma unroll
        for (int nt = 0; nt < 6; ++nt)
            acc[mt][nt] = (f32x4){0.f, 0.f, 0.f, 0.f};

    const unsigned short* Bbase = src + (size_t)b0 * 64 * 96 * 8;

    for (int kc2 = 0; kc2 < 8; ++kc2) {          // K-chunk of 64
        // ---- A-frags for this chunk: direct global (L2-hot), coalesced 1KB/wave
        bf16x8 af[4][2];
        #pragma unroll
        for (int mt = 0; mt < 4; ++mt) {
            int rg = mtile * 8 + (wv & 1) * 4 + mt;   // 16-row group
            #pragma unroll
            for (int sub = 0; sub < 2; ++sub) {
                int kc = kc2 * 2 + sub;               // kc32 index
                af[mt][sub] = *(const bf16x8*)(At_fr + ((size_t)(rg * 16 + kc) * 512) + lane * 8);
            }
        }

        __syncthreads();
        // ---- stage B: 2 b x 96 l x 64 v  (1536 x 16B, coalesced in l) ----
        #pragma unroll
        for (int i = 0; i < 6; ++i) {
            int g = tid + i * 256;                // 0..1535
            int bs = g / 768;
            int rem = g % 768;
            int q = rem / 96, l = rem % 96;       // q = v-slot within chunk (0..7)
            uint4 val = *(const uint4*)(Bbase + (((size_t)bs * 64 + kc2 * 8 + q) * 96 + l) * 8);
            *(uint4*)&Bsh[(((bs * 96 + l) * 8) + swz8(l, q)) * 8] = val;
        }
        __syncthreads();

        // ---- 48 MFMAs/wave ----
        #pragma unroll
        for (int sub = 0; sub < 2; ++sub) {
            #pragma unroll
            for (int nt = 0; nt < 6; ++nt) {
                int l = nt * 16 + col;
                bf16x8 bfr = *(const bf16x8*)&Bsh[(((bsel * 96 + l) * 8) + swz8(l, sub * 4 + q4)) * 8];
                #pragma unroll
                for (int mt = 0; mt < 4; ++mt)
                    acc[mt][nt] = __builtin_amdgcn_mfma_f32_16x16x32_bf16(
                        af[mt][sub], bfr, acc[mt][nt], 0, 0, 0);
            }
        }
    }

    // C/D layout: col = lane&15 (n=l), row = q4*4+reg (m=w). 4 regs = 4 consecutive w.
    const size_t b = b0 + bsel;
    #pragma unroll
    for (int mt = 0; mt < 4; ++mt) {
        int w0 = mtile * 128 + mhalf + mt * 16 + q4 * 4;
        int vblk = w0 >> 3, vv0 = w0 & 7;   // vv0 in {0,4}
        #pragma unroll
        for (int nt = 0; nt < 6; ++nt) {
            int l = nt * 16 + col;
            uint2 u;
            u.x = (unsigned)f2bf(acc[mt][nt].x) | ((unsigned)f2bf(acc[mt][nt].y) << 16);
            u.y = (unsigned)f2bf(acc[mt][nt].z) | ((unsigned)f2bf(acc[mt][nt].w) << 16);
            *(uint2*)(dst + ((b * 64 + vblk) * 96 + l) * 8 + vv0) = u;
        }
    }
}

// ---------------------------------------------------------------------------
// proj v2: out[n][o][v][l] = PReLU(sum_c Wo[o][c]*h[c][v][l] + bout[o])
// h planes: c<32 -> xt, <64 -> x1, else x2.
// Block = (vblk, n), 512 threads / 8 waves. Wave wv owns vv = wv, all 96 l.
// col = vv*96 + l  ->  each (o,v) output row's 6x64B segments are stored
// back-to-back by the same lanes => full-line L2 merges, no cross-block RMW.
// ---------------------------------------------------------------------------
__global__ __launch_bounds__(512, 1)
void proj_kernel(const unsigned short* __restrict__ Wo,
                 const unsigned short* __restrict__ xt,
                 const unsigned short* __restrict__ x1,
                 const unsigned short* __restrict__ x2,
                 const float* __restrict__ bout,
                 const float* __restrict__ prelu_a,
                 float* __restrict__ out)
{
    __shared__ unsigned short WoSh[64 * 12 * 8]; // 12KB: [o][slot(12)][8]
    __shared__ unsigned short Bsh[768 * 4 * 8];  // 48KB: [col=vv*96+l][slot][8]

    const int vblk = blockIdx.x;  // 0..62
    const int n = blockIdx.y;     // 0..31
    const int tid = threadIdx.x;
    const int lane = tid & 63, wv = tid >> 6;   // wv = vv owned by this wave
    const int colL = lane & 15, q4 = lane >> 4;

    for (int g = tid; g < 768; g += 512) {
        int o = g / 12, slot = g % 12;
        int kc = slot >> 2, qq = slot & 3;
        uint4 val = *(const uint4*)(Wo + o * 96 + slot * 8);
        *(uint4*)&WoSh[(o * 12 + kc * 4 + swz(o, qq)) * 8] = val;
    }

    f32x4 acc[4][6];
    #pragma unroll
    for (int mt = 0; mt < 4; ++mt)
        #pragma unroll
        for (int nt = 0; nt < 6; ++nt)
            acc[mt][nt] = (f32x4){0.f, 0.f, 0.f, 0.f};

    const unsigned short* planes[3] = {xt, x1, x2};
    for (int kc = 0; kc < 3; ++kc) {
        __syncthreads();
        const unsigned short* P = planes[kc];
        // stage + transpose one full plane slice [32c][96l][8vv] -> Bsh[col][c]
        #pragma unroll
        for (int s = 0; s < 6; ++s) {
            int idx = tid + s * 512;              // 0..3071
            int cl = idx / 96, l = idx % 96;      // c_local 0..31, l 0..95
            union { uint4 u; unsigned short sh[8]; } val;
            val.u = *(const uint4*)(P + (((size_t)(n * 32 + cl)) * 64 + vblk) * 96 * 8
                                      + (size_t)l * 8);
            int cq = cl >> 3, cw = cl & 7;
            #pragma unroll
            for (int vv = 0; vv < 8; ++vv) {
                int colv = vv * 96 + l;
                Bsh[(colv * 4 + swz(colv, cq)) * 8 + cw] = val.sh[vv];
            }
        }
        __syncthreads();

        bf16x8 af[4], bfr[6];
        #pragma unroll
        for (int mt = 0; mt < 4; ++mt) {
            int o = mt * 16 + colL;
            af[mt] = *(const bf16x8*)&WoSh[(o * 12 + kc * 4 + swz(o, q4)) * 8];
        }
        #pragma unroll
        for (int nt = 0; nt < 6; ++nt) {
            int colv = wv * 96 + nt * 16 + colL;
            bfr[nt] = *(const bf16x8*)&Bsh[(colv * 4 + swz(colv, q4)) * 8];
        }
        #pragma unroll
        for (int mt = 0; mt < 4; ++mt)
            #pragma unroll
            for (int nt = 0; nt < 6; ++nt)
                acc[mt][nt] = __builtin_amdgcn_mfma_f32_16x16x32_bf16(
                    af[mt], bfr[nt], acc[mt][nt], 0, 0, 0);
    }

    const float pa = prelu_a[0];
    const int v = vblk * 8 + wv;
    if (v < 500) {
        #pragma unroll
        for (int mt = 0; mt < 4; ++mt) {
            #pragma unroll
            for (int r = 0; r < 4; ++r) {
                int o = mt * 16 + q4 * 4 + r;
                float bo = bout[o];
                float* orow = out + (((size_t)n * 64 + o) * 500 + v) * 94;
                #pragma unroll
                for (int nt = 0; nt < 6; ++nt) {
                    int l = nt * 16 + colL;
                    if (l < 94) {
                        float val = acc[mt][nt][r] + bo;
                        val = (val > 0.f) ? val : pa * val;
                        orow[l] = val;
                    }
                }
            }
        }
    }
}

// ---------------------------------------------------------------------------
extern "C" void kernel_launch(void* const* d_in, const int* in_sizes, int n_in,
                              void* d_out, int out_size, void* d_ws, size_t ws_size,
                              hipStream_t stream)
{
    const float* x    = (const float*)d_in[0];
    const float* A    = (const float*)d_in[1];
    const float* w1   = (const float*)d_in[2];
    const float* b1   = (const float*)d_in[3];
    const float* w2   = (const float*)d_in[4];
    const float* b2   = (const float*)d_in[5];
    const float* w3   = (const float*)d_in[6];
    const float* b3   = (const float*)d_in[7];
    const float* wout = (const float*)d_in[8];
    const float* bout = (const float*)d_in[9];
    const float* pa   = (const float*)d_in[10];
    float* out = (float*)d_out;

    char* ws = (char*)d_ws;
    unsigned short* xt = (unsigned short*)(ws);
    unsigned short* x1 = (unsigned short*)(ws + WS_S);
    unsigned short* x2 = (unsigned short*)(ws + 2 * WS_S);
    unsigned short* At = (unsigned short*)(ws + 3 * WS_S);
    unsigned short* Wa = (unsigned short*)(ws + 3 * WS_S + AT_B);
    unsigned short* Wo = (unsigned short*)(ws + 3 * WS_S + AT_B + WA_B);

    const int prep_elems = 512 * 512 + 3 * 3 * 32 * 32 + 64 * 96;
    prep_kernel<<<dim3((prep_elems + 255) / 256), 256, 0, stream>>>(
        A, w1, w2, w3, wout, At, Wa, Wo);
    conv_kernel<<<dim3(2, 63, 32), 512, 0, stream>>>(x, Wa, b1, b2, b3, xt);
    hop_kernel<<<dim3(2048), 256, 0, stream>>>(At, xt, x1);
    hop_kernel<<<dim3(2048), 256, 0, stream>>>(At, x1, x2);
    proj_kernel<<<dim3(63, 32), 512, 0, stream>>>(Wo, xt, x1, x2, bout, pa, out);
}